// Round 13
// baseline (79.977 us; speedup 1.0000x reference)
//
#include <hip/hip_runtime.h>

// CapsuleConv2d fused, MI355X gfx950. ALL I/O FP32.
// B=2, C_in=128 (G=8 x M=16), 32x32, 3x3 pad 1, O=16, L=16 -> C_out=256.
// k-means (dot) routing 3 iters + squash.
//
// v10 = v9 (MFMA priors; verified R12, absmax 4.9e-4) with the fp32->bf16
// hi/lo SPLIT and BOUNDARY MASKING moved into prep:
//   xS[b][34][34][hi|lo][128c] bf16, zero border -> main-kernel A fragment is
//   two raw dwordx4 loads. Phase-1 per-thread ~650 -> ~270 inst.
// Per ij: C[32=4p*8g x 32t] += A[32x16m] @ B[16mx32t] via 3x
// v_mfma_f32_32x32x16_bf16 (hiA*loB + loA*hiB + hiA*hiB).
// C (col=lane&31, row=(reg&3)+8*(reg>>2)+4*(lane>>5)) -> u LDS [4p][72n][32t].
// Phase 2: v8-lineage scalarized register-local routing per pixel-wave.
// NOTE (R12): the ~41 us __amd_rocclr_fillBufferAligned (268 MB d_ws 0xAA
// re-poison) is harness overhead, present in every timed iteration.

typedef float v2f __attribute__((ext_vector_type(2)));
typedef int   i4  __attribute__((ext_vector_type(4)));
typedef short bh8 __attribute__((ext_vector_type(8)));
typedef float f16v __attribute__((ext_vector_type(16)));

#define XS_U16   (2 * 34 * 34 * 256)   // padded split planes, 1.16 MB
#define WBF_U16  (9 * 8 * 2 * 64 * 8)  // 73728 u16 = 144 KB
#define STR 34                         // u LDS row stride (floats)

#define DPP_ADD(a, ctrl)                                                     \
  a += __int_as_float(__builtin_amdgcn_update_dpp(                           \
          0, __float_as_int(a), ctrl, 0xF, 0xF, true))

__device__ __forceinline__ float dpp_add16(float x) {
    float s = x;
    DPP_ADD(s, 0x128); DPP_ADD(s, 0x124); DPP_ADD(s, 0x122); DPP_ADD(s, 0x121);
    return s;
}

__device__ __forceinline__ float swz16_add(float x) {
    int y = __builtin_amdgcn_ds_swizzle(__float_as_int(x), 0x401F);
    return x + __int_as_float(y);
}

__device__ __forceinline__ float frcp(float x) {
    return __builtin_amdgcn_rcpf(x);
}

__device__ __forceinline__ v2f pkfma(v2f a, v2f b, v2f c) {
    return __builtin_elementwise_fma(a, b, c);
}

// ---- prep ----
// blocks [0,64):   interior transpose+split: xS[b][h+1][w+1][s][c]
// blocks [64,97):  zero border pixels (264 pixels x 128 u32)
// blocks [97,385): Wbf B-fragment pack (v9-verified layout)
__global__ __launch_bounds__(256)
void prep_kernel(const float* __restrict__ x, const float* __restrict__ W,
                 unsigned int* __restrict__ xS32,
                 unsigned short* __restrict__ Wbf) {
    const int blk = blockIdx.x;
    const int tid = threadIdx.x;
    if (blk < 64) {
        __shared__ float xs[128 * 33];
        const int b = blk >> 5, h = blk & 31;
        const float* xb = x + b * (128 * 32 * 32) + h * 32;
        #pragma unroll
        for (int k = 0; k < 16; ++k) {
            int idx = k * 256 + tid;
            int c = idx >> 5, w = idx & 31;
            xs[c * 33 + w] = xb[c * 1024 + w];       // coalesced
        }
        __syncthreads();
        // write 32 pixels x 128 u32 (hi plane 64, lo plane 64)
        #pragma unroll
        for (int k = 0; k < 16; ++k) {
            int idx = k * 256 + tid;                 // 0..4095
            int w   = idx >> 7;
            int s32 = idx & 127;
            int pl  = s32 >> 6;                      // 0 hi, 1 lo
            int cp  = s32 & 63;
            float v0 = xs[(2 * cp) * 33 + w];
            float v1 = xs[(2 * cp + 1) * 33 + w];
            unsigned b0 = __float_as_uint(v0), b1 = __float_as_uint(v1);
            unsigned outw;
            if (pl == 0) {
                outw = (b0 >> 16) | (b1 & 0xFFFF0000u);
            } else {
                unsigned l0 = __float_as_uint(v0 - __uint_as_float(b0 & 0xFFFF0000u));
                unsigned l1 = __float_as_uint(v1 - __uint_as_float(b1 & 0xFFFF0000u));
                outw = (l0 >> 16) | (l1 & 0xFFFF0000u);
            }
            xS32[(((b * 34 + h + 1) * 34) + (w + 1)) * 128 + s32] = outw;
        }
    } else if (blk < 97) {
        // zero 264 border pixels, 8 per block
        int task = (blk - 64) * 8 + (tid >> 5);      // 0..263
        int t32 = tid & 31;
        int b = task / 132, k = task - b * 132;
        int hp, wp;
        if (k < 34)      { hp = 0;  wp = k; }
        else if (k < 68) { hp = 33; wp = k - 34; }
        else { int k2 = k - 68; hp = 1 + (k2 >> 1); wp = (k2 & 1) ? 33 : 0; }
        unsigned int* base = xS32 + (((b * 34 + hp) * 34) + wp) * 128;
        #pragma unroll
        for (int i = 0; i < 4; ++i) base[i * 32 + t32] = 0u;
    } else {
        int idx = (blk - 97) * 256 + tid;            // 0..73727
        int j  = idx & 7;
        int L  = (idx >> 3) & 63;
        int s  = (idx >> 9) & 1;
        int tt = (idx >> 10) & 7;
        int ij = idx >> 13;
        int k  = (L >> 5) * 8 + j;
        int t  = tt * 32 + (L & 31);
        float wv = W[(t * 16 + k) * 9 + ij];
        unsigned bits = __float_as_uint(wv);
        unsigned hib  = bits & 0xFFFF0000u;
        unsigned short val;
        if (s == 0) val = (unsigned short)(hib >> 16);
        else {
            float lo = wv - __uint_as_float(hib);
            val = (unsigned short)(__float_as_uint(lo) >> 16);
        }
        Wbf[idx] = val;
    }
}

// ---- phase-1 macro: one ij tile -> 3x MFMA -> u LDS scatter ----
#define CWR(REG, IJ)                                                         \
    uLds[wroff + STR * ((((REG) >> 2) * 72) + (((REG) & 3) * 9) + (IJ))] =   \
        acc[(REG)];

#define DO_IJ(IJ)                                                            \
  { const int di = (IJ) / 3, dj = (IJ) % 3;                                  \
    const unsigned short* ap = xS +                                          \
        (((bb * 34 + h + di) * 34) + (w0 + pl + dj)) * 256 + cofs;           \
    i4 ahw = *(const i4*)ap;                                                 \
    i4 alw = *(const i4*)(ap + 128);                                         \
    i4 bhiw = bfr[((IJ) * 8 + tt) * 128 + lane];                             \
    i4 blow = bfr[((IJ) * 8 + tt) * 128 + 64 + lane];                        \
    bh8 aHi = __builtin_bit_cast(bh8, ahw);                                  \
    bh8 aLo = __builtin_bit_cast(bh8, alw);                                  \
    bh8 bHi = __builtin_bit_cast(bh8, bhiw);                                 \
    bh8 bLo = __builtin_bit_cast(bh8, blow);                                 \
    f16v acc = {0.f,0.f,0.f,0.f,0.f,0.f,0.f,0.f,                             \
                0.f,0.f,0.f,0.f,0.f,0.f,0.f,0.f};                            \
    acc = __builtin_amdgcn_mfma_f32_32x32x16_bf16(aHi, bLo, acc, 0, 0, 0);   \
    acc = __builtin_amdgcn_mfma_f32_32x32x16_bf16(aLo, bHi, acc, 0, 0, 0);   \
    acc = __builtin_amdgcn_mfma_f32_32x32x16_bf16(aHi, bHi, acc, 0, 0, 0);   \
    CWR(0, IJ)  CWR(1, IJ)  CWR(2, IJ)  CWR(3, IJ)                           \
    CWR(4, IJ)  CWR(5, IJ)  CWR(6, IJ)  CWR(7, IJ)                           \
    CWR(8, IJ)  CWR(9, IJ)  CWR(10, IJ) CWR(11, IJ)                          \
    CWR(12, IJ) CWR(13, IJ) CWR(14, IJ) CWR(15, IJ) }

// ---- phase-2 macros (5 rows x 8 l per thread, scalarized) ----
#define LROW(K)                                                              \
  { const v2f* r2_ = (const v2f*)(rb + (K) * 16 * STR);                      \
    U##K##0 = r2_[0]; U##K##1 = r2_[1]; U##K##2 = r2_[2]; U##K##3 = r2_[3]; }

#define DOTR(K)                                                              \
  ({ v2f d_ = U##K##0 * V0;                                                  \
     d_ = pkfma(U##K##1, V1, d_); d_ = pkfma(U##K##2, V2, d_);               \
     d_ = pkfma(U##K##3, V3, d_); swz16_add(d_.x + d_.y); })

#define MEANJ(J)                                                             \
  { v2f s_ = (U0##J + U1##J) + (U2##J + U3##J) + U4##J;                      \
    V##J.x = dpp_add16(s_.x) * (1.0f / 72.0f);                               \
    V##J.y = dpp_add16(s_.y) * (1.0f / 72.0f); }

#define UPDJ(J)                                                              \
  { v2f pv_ = e0v * U0##J;                                                   \
    pv_ = pkfma(e1v, U1##J, pv_); pv_ = pkfma(e2v, U2##J, pv_);              \
    pv_ = pkfma(e3v, U3##J, pv_); pv_ = pkfma(e4v, U4##J, pv_);              \
    V##J.x = dpp_add16(pv_.x) * rs;                                          \
    V##J.y = dpp_add16(pv_.y) * rs; }

// ---- main kernel v10: block = 4 pixels x 32 t-cols ----
__global__ __launch_bounds__(256, 4)
void capsule_v10(const unsigned short* __restrict__ xS,
                 const unsigned short* __restrict__ Wbf,
                 float* __restrict__ out) {
    __shared__ float uLds[4 * 72 * STR];     // 38.25 KB
    const int blk = blockIdx.x;              // 4096
    const int tt = blk & 7;                  // t-tile (32 cols)
    const int q  = blk >> 3;                 // pixel quad
    const int bb = q >> 8;
    const int r  = q & 255;
    const int h  = r >> 3;
    const int w0 = (r & 7) << 2;
    const int tid = threadIdx.x;

    // ---- phase 1: MFMA priors ----
    {
        const int lane = tid & 63;
        const int wv   = tid >> 6;
        const int pl   = (lane & 31) >> 3;   // pixel in quad (A row>>3)
        const int gl   = lane & 7;           // group (A row&7)
        const int half = lane >> 5;          // k-half
        const int tl   = lane & 31;          // C col
        const int cofs = gl * 16 + half * 8;
        const int wroff = tl + STR * 9 * 4 * half;
        const i4* bfr = (const i4*)Wbf;
        if (wv == 0)      { DO_IJ(0) DO_IJ(4) DO_IJ(8) }
        else if (wv == 1) { DO_IJ(1) DO_IJ(5) }
        else if (wv == 2) { DO_IJ(2) DO_IJ(6) }
        else              { DO_IJ(3) DO_IJ(7) }
    }
    __syncthreads();

    // ---- phase 2: routing. wave = pixel; (o2, jh, sc) in-wave ----
    const int p  = tid >> 6;
    const int i6 = tid & 63;
    const int o2 = i6 >> 5;
    const int jh = (i6 >> 4) & 1;
    const int sc = i6 & 15;
    const bool has5 = (sc < 8);
    const float* rb = uLds + (p * 72 + sc) * STR + o2 * 16 + jh * 8;

    v2f U00, U01, U02, U03;
    v2f U10, U11, U12, U13;
    v2f U20, U21, U22, U23;
    v2f U30, U31, U32, U33;
    v2f U40, U41, U42, U43;
    U40 = U41 = U42 = U43 = (v2f){0.0f, 0.0f};
    LROW(0) LROW(1) LROW(2) LROW(3)
    if (has5) LROW(4)

    v2f V0, V1, V2, V3;
    MEANJ(0) MEANJ(1) MEANJ(2) MEANJ(3)

    #pragma unroll 1
    for (int it = 0; it < 3; ++it) {
        v2f ssv = V0 * V0;
        ssv = pkfma(V1, V1, ssv); ssv = pkfma(V2, V2, ssv);
        ssv = pkfma(V3, V3, ssv);
        float ss = swz16_add(ssv.x + ssv.y);
        float inv = frcp(fmaxf(sqrtf(ss), 1e-12f));

        float E0 = __expf(DOTR(0) * inv);
        float E1 = __expf(DOTR(1) * inv);
        float E2 = __expf(DOTR(2) * inv);
        float E3 = __expf(DOTR(3) * inv);
        float E4 = has5 ? __expf(DOTR(4) * inv) : 0.0f;
        float ssum = dpp_add16(((E0 + E1) + (E2 + E3)) + E4);
        float rs = frcp(ssum);

        v2f e0v = {E0, E0}, e1v = {E1, E1}, e2v = {E2, E2};
        v2f e3v = {E3, E3}, e4v = {E4, E4};
        UPDJ(0) UPDJ(1) UPDJ(2) UPDJ(3)
    }

    v2f ssv = V0 * V0;
    ssv = pkfma(V1, V1, ssv); ssv = pkfma(V2, V2, ssv);
    ssv = pkfma(V3, V3, ssv);
    float ss = swz16_add(ssv.x + ssv.y);
    float scale = sqrtf(ss) * frcp(1.0f + ss);

    v2f aa0 = (sc & 4) ? V2 : V0;
    v2f aa1 = (sc & 4) ? V3 : V1;
    v2f bb0 = (sc & 2) ? aa1 : aa0;
    float res = ((sc & 1) ? bb0.y : bb0.x) * scale;
    if (sc < 8) {
        int tg = tt * 32 + o2 * 16 + jh * 8 + sc;
        out[((bb * 256 + tg) * 32 + h) * 32 + w0 + p] = res;
    }
}

// ---- fallback (tiny ws): self-contained ----
__global__ __launch_bounds__(256, 1)
void capsule_fb(const float* __restrict__ x, const float* __restrict__ Wraw,
                float* __restrict__ out) {
    __shared__ float patch[9 * 128];
    const int blk = blockIdx.x;
    const int b = blk >> 10, h = (blk >> 5) & 31, w = blk & 31;
    const int t = threadIdx.x;

    const float* xb = x + b * (128 * 32 * 32);
    for (int idx = t; idx < 1152; idx += 256) {
        int c = idx / 9, ij = idx - c * 9;
        int di = ij / 3, dj = ij - di * 3;
        int hh = h + di - 1, ww = w + dj - 1;
        float v = 0.0f;
        if ((unsigned)hh < 32u && (unsigned)ww < 32u)
            v = xb[(c * 32 + hh) * 32 + ww];
        patch[ij * 128 + c] = v;
    }
    __syncthreads();

    float u[72];
    #pragma unroll
    for (int ij = 0; ij < 9; ++ij) {
        float wr[16];
        #pragma unroll
        for (int m = 0; m < 16; ++m) wr[m] = Wraw[(t * 16 + m) * 9 + ij];
        #pragma unroll
        for (int g = 0; g < 8; ++g) {
            float acc = 0.0f;
            #pragma unroll
            for (int m = 0; m < 16; ++m)
                acc = fmaf(patch[ij * 128 + g * 16 + m], wr[m], acc);
            u[g * 9 + ij] = acc;
        }
    }

    float v = 0.0f;
    #pragma unroll
    for (int n = 0; n < 72; ++n) v += u[n];
    v *= (1.0f / 72.0f);
    #pragma unroll 1
    for (int it = 0; it < 3; ++it) {
        float sg = dpp_add16(v * v);
        float vn = v * frcp(fmaxf(sqrtf(sg), 1e-12f));
        float ssum = 0.0f, vacc = 0.0f;
        #pragma unroll
        for (int n = 0; n < 72; ++n) {
            float pp = dpp_add16(u[n] * vn);
            float e = __expf(pp);
            ssum += e;
            vacc = fmaf(e, u[n], vacc);
        }
        v = vacc * frcp(ssum);
    }
    float sg = dpp_add16(v * v);
    float res = v * sqrtf(sg) * frcp(1.0f + sg);
    out[((b * 256 + t) * 32 + h) * 32 + w] = res;
}

extern "C" void kernel_launch(void* const* d_in, const int* in_sizes, int n_in,
                              void* d_out, int out_size, void* d_ws, size_t ws_size,
                              hipStream_t stream) {
    const float* x = (const float*)d_in[0];   // [2,128,32,32]
    const float* W = (const float*)d_in[1];   // [16,16,16,3,3]
    float* out = (float*)d_out;               // [2,256,32,32]
    unsigned int*   xS32 = (unsigned int*)d_ws;
    unsigned short* xS   = (unsigned short*)d_ws;
    unsigned short* Wbf  = (unsigned short*)d_ws + XS_U16;

    const size_t need = (size_t)(XS_U16 + WBF_U16) * 2;
    if (ws_size >= need) {
        prep_kernel<<<385, 256, 0, stream>>>(x, W, xS32, Wbf);
        capsule_v10<<<4096, 256, 0, stream>>>(xS, Wbf, out);
    } else {
        capsule_fb<<<2048, 256, 0, stream>>>(x, W, out);
    }
}